// Round 4
// baseline (1266.967 us; speedup 1.0000x reference)
//
#include <hip/hip_runtime.h>
#include <hip/hip_bf16.h>
#include <math.h>

typedef __hip_bfloat16 bf16;
typedef __attribute__((ext_vector_type(8))) short short8;
typedef __attribute__((ext_vector_type(4))) float float4_;

#define B_   2
#define T_   2048
#define D_   1024
#define H_   16
#define NTOK (B_ * T_)
#define NEG_SENT -1e30f

static __device__ __forceinline__ float b2f(bf16 v) { return __bfloat162float(v); }
static __device__ __forceinline__ bf16  f2b(float v) { return __float2bfloat16(v); }
static __device__ __forceinline__ short f2s(float v) {  // fp32 -> bf16 bits (RNE)
    unsigned u = __builtin_bit_cast(unsigned, v);
    unsigned r = (u + 0x7FFFu + ((u >> 16) & 1u)) >> 16;
    return (short)r;
}
static __device__ __forceinline__ float to_f(float v) { return v; }
static __device__ __forceinline__ float to_f(bf16 v) { return __bfloat162float(v); }
static __device__ __forceinline__ void  store_o(float* p, float v) { *p = v; }
static __device__ __forceinline__ void  store_o(bf16* p, float v) { *p = __float2bfloat16(v); }

// ---------------- RMSNorm over D=1024 (one block per token), fp32 in, bf16 out
__global__ __launch_bounds__(256) void rmsnorm_k(const float* __restrict__ x,
                                                 const float* __restrict__ w,
                                                 bf16* __restrict__ out) {
    int t = blockIdx.x, tid = threadIdx.x;
    float xs[4], ss = 0.f;
#pragma unroll
    for (int i = 0; i < 4; ++i) {
        float v = x[(size_t)t * D_ + tid + i * 256];
        xs[i] = v; ss += v * v;
    }
    __shared__ float red[4];
#pragma unroll
    for (int off = 32; off > 0; off >>= 1) ss += __shfl_xor(ss, off, 64);
    if ((tid & 63) == 0) red[tid >> 6] = ss;
    __syncthreads();
    ss = red[0] + red[1] + red[2] + red[3];
    float inv = rsqrtf(ss * (1.f / D_) + 1e-6f);
#pragma unroll
    for (int i = 0; i < 4; ++i) {
        int c = tid + i * 256;
        out[(size_t)t * D_ + c] = f2b(xs[i] * inv * w[c]);
    }
}

// ------- fused modulate (x = x*(1+scale1)+shift1, in place fp32) + RMSNorm2 --
__global__ __launch_bounds__(256) void modnorm_k(float* __restrict__ x1,
                                                 const bf16* __restrict__ mod, // [NTOK][2048] = shift|scale
                                                 const float* __restrict__ w,
                                                 bf16* __restrict__ h2) {
    int t = blockIdx.x, tid = threadIdx.x;
    float xs[4], ss = 0.f;
#pragma unroll
    for (int i = 0; i < 4; ++i) {
        int c = tid + i * 256;
        float sh = b2f(mod[(size_t)t * 2048 + c]);
        float sc = b2f(mod[(size_t)t * 2048 + 1024 + c]);
        float v = x1[(size_t)t * D_ + c] * (1.f + sc) + sh;
        xs[i] = v; ss += v * v;
        x1[(size_t)t * D_ + c] = v;
    }
    __shared__ float red[4];
#pragma unroll
    for (int off = 32; off > 0; off >>= 1) ss += __shfl_xor(ss, off, 64);
    if ((tid & 63) == 0) red[tid >> 6] = ss;
    __syncthreads();
    ss = red[0] + red[1] + red[2] + red[3];
    float inv = rsqrtf(ss * (1.f / D_) + 1e-6f);
#pragma unroll
    for (int i = 0; i < 4; ++i) {
        int c = tid + i * 256;
        h2[(size_t)t * D_ + c] = f2b(xs[i] * inv * w[c]);
    }
}

// ------------- per-head RMSNorm for q and k, in place (HD=64, bf16 internal) -
__global__ __launch_bounds__(256) void qknorm_k(bf16* __restrict__ q, bf16* __restrict__ k,
                                                const float* __restrict__ qw,
                                                const float* __restrict__ kw) {
    int bid = blockIdx.x;
    int t = bid >> 2;
    int h = (bid & 3) * 4 + (threadIdx.x >> 6);
    int lane = threadIdx.x & 63;
    size_t idx = (size_t)t * D_ + h * 64 + lane;
    float qv = b2f(q[idx]);
    float ss = qv * qv;
#pragma unroll
    for (int off = 32; off > 0; off >>= 1) ss += __shfl_xor(ss, off, 64);
    q[idx] = f2b(qv * rsqrtf(ss * (1.f / 64.f) + 1e-6f) * qw[lane]);
    float kv = b2f(k[idx]);
    ss = kv * kv;
#pragma unroll
    for (int off = 32; off > 0; off >>= 1) ss += __shfl_xor(ss, off, 64);
    k[idx] = f2b(kv * rsqrtf(ss * (1.f / 64.f) + 1e-6f) * kw[lane]);
}

// ------------- ae1: [NTOK,16] @ [16,1024] + b, SiLU (fp32 in, bf16 out) -----
__global__ __launch_bounds__(256) void ae1_k(const float* __restrict__ actions,
                                             const float* __restrict__ w,
                                             const float* __restrict__ b,
                                             bf16* __restrict__ out) {
    int t = blockIdx.x, tid = threadIdx.x;
    float av[16];
#pragma unroll
    for (int a = 0; a < 16; ++a) av[a] = actions[(size_t)t * 16 + a];
#pragma unroll
    for (int i = 0; i < 4; ++i) {
        int n = tid + i * 256;
        float acc = b[n];
#pragma unroll
        for (int a = 0; a < 16; ++a) acc += av[a] * w[a * D_ + n];
        out[(size_t)t * D_ + n] = f2b(acc / (1.f + expf(-acc)));
    }
}

// ------------- MFMA GEMM: C = A[M,K](bf16) @ W[K,N](fp32) + bias(fp32) ------
// ACT: 0 none, 1 SiLU, 2 GELU(exact). res (same [M,N]) added after ACT.
// res==out aliasing safe: per-element read-then-write, disjoint addresses.
// ldw = row stride of W (W is [K, >=N], may be a column-slice of a wider mat).
template <int ACT, typename ResT, typename OutT>
__global__ __launch_bounds__(256) void gemm_k(const bf16* __restrict__ A,
                                              const float* __restrict__ W,
                                              const float* __restrict__ bias,
                                              const ResT* __restrict__ res,
                                              OutT* __restrict__ out,
                                              int M, int N, int K, int ldw) {
    __shared__ __align__(16) short As[128 * 72];   // [m][k], stride 72
    __shared__ __align__(16) short Bs[128 * 72];   // transposed: [n][k], stride 72
    const int tid = threadIdx.x;
    const int bm = blockIdx.y * 128, bn = blockIdx.x * 128;
    const int wave = tid >> 6, lane = tid & 63;
    const int wm = (wave & 1) * 64, wn = (wave >> 1) * 64;
    const int l15 = lane & 15, quad = lane >> 4;
    float4_ acc[4][4] = {};

    for (int k0 = 0; k0 < K; k0 += 64) {
#pragma unroll
        for (int it = 0; it < 4; ++it) {           // A tile 128x64 (bf16)
            int c = tid + it * 256;
            int row = c >> 3, col8 = (c & 7) << 3;
            short8 v = *(const short8*)((const short*)A + (size_t)(bm + row) * K + k0 + col8);
            *(short8*)&As[row * 72 + col8] = v;
        }
#pragma unroll
        for (int it = 0; it < 4; ++it) {           // W tile 64x128 (fp32->bf16), transposed
            int c = tid + it * 256;
            int krow = c >> 4, n8 = (c & 15) << 3;
            const float* wp = W + (size_t)(k0 + krow) * ldw + bn + n8;
            float4_ w0 = *(const float4_*)wp;
            float4_ w1 = *(const float4_*)(wp + 4);
#pragma unroll
            for (int j = 0; j < 4; ++j) Bs[(n8 + j) * 72 + krow]     = f2s(w0[j]);
#pragma unroll
            for (int j = 0; j < 4; ++j) Bs[(n8 + 4 + j) * 72 + krow] = f2s(w1[j]);
        }
        __syncthreads();
#pragma unroll
        for (int kk = 0; kk < 64; kk += 32) {
            short8 af[4], bfr[4];
#pragma unroll
            for (int i = 0; i < 4; ++i)
                af[i] = *(const short8*)&As[(wm + i * 16 + l15) * 72 + kk + quad * 8];
#pragma unroll
            for (int j = 0; j < 4; ++j)
                bfr[j] = *(const short8*)&Bs[(wn + j * 16 + l15) * 72 + kk + quad * 8];
#pragma unroll
            for (int i = 0; i < 4; ++i)
#pragma unroll
                for (int j = 0; j < 4; ++j)
                    acc[i][j] = __builtin_amdgcn_mfma_f32_16x16x32_bf16(af[i], bfr[j], acc[i][j], 0, 0, 0);
        }
        __syncthreads();
    }

#pragma unroll
    for (int i = 0; i < 4; ++i) {
#pragma unroll
        for (int j = 0; j < 4; ++j) {
            int col = bn + wn + j * 16 + l15;
            float bv = bias[col];
#pragma unroll
            for (int r = 0; r < 4; ++r) {
                int row = bm + wm + i * 16 + quad * 4 + r;
                float v = acc[i][j][r] + bv;
                if (ACT == 1) v = v / (1.f + expf(-v));
                else if (ACT == 2) v = 0.5f * v * (1.f + erff(v * 0.70710678118654752f));
                if (res) v += to_f(res[(size_t)row * N + col]);
                store_o(&out[(size_t)row * N + col], v);
            }
        }
    }
}

// -------------- flash attention, causal, HD=64, MFMA 16x16x32 (bf16) --------
// grid: (T/64, B*H). block: 256 = 4 waves, each wave owns 16 q-rows.
__global__ __launch_bounds__(256) void attn_k(const bf16* __restrict__ Q,
                                              const bf16* __restrict__ K,
                                              const bf16* __restrict__ V,
                                              bf16* __restrict__ O) {
    __shared__ __align__(16) short Ks[32 * 72];     // [kv][hd]
    __shared__ __align__(16) short Vt[64 * 40];     // [hd][kv]
    __shared__ __align__(16) short Ps[4][16 * 40];  // per-wave [q][kv]
    const int bh = blockIdx.y, b = bh >> 4, h = bh & 15;
    const int q0 = blockIdx.x * 64;
    const int tid = threadIdx.x, wave = tid >> 6, lane = tid & 63;
    const int l15 = lane & 15, quad = lane >> 4;
    const size_t base = (size_t)b * T_ * D_ + h * 64;

    const int qrow = q0 + wave * 16 + l15;
    short8 qf0 = *(const short8*)((const short*)Q + base + (size_t)qrow * D_ + quad * 8);
    short8 qf1 = *(const short8*)((const short*)Q + base + (size_t)qrow * D_ + 32 + quad * 8);

    float4_ oacc[4] = {};
    float m_r[4], l_r[4];
#pragma unroll
    for (int r = 0; r < 4; ++r) { m_r[r] = NEG_SENT; l_r[r] = 0.f; }

    for (int kv0 = 0; kv0 < q0 + 64; kv0 += 32) {
        {   // stage K (verbatim) and V (transposed)
            int kvrow = tid >> 3, col8 = (tid & 7) << 3;
            short8 kv = *(const short8*)((const short*)K + base + (size_t)(kv0 + kvrow) * D_ + col8);
            *(short8*)&Ks[kvrow * 72 + col8] = kv;
            short8 vv = *(const short8*)((const short*)V + base + (size_t)(kv0 + kvrow) * D_ + col8);
#pragma unroll
            for (int j = 0; j < 8; ++j) Vt[(col8 + j) * 40 + kvrow] = vv[j];
        }
        __syncthreads();

        float4_ s[2];
#pragma unroll
        for (int c = 0; c < 2; ++c) {
            short8 b0 = *(const short8*)&Ks[(c * 16 + l15) * 72 + quad * 8];
            short8 b1 = *(const short8*)&Ks[(c * 16 + l15) * 72 + 32 + quad * 8];
            float4_ sc = {};
            sc = __builtin_amdgcn_mfma_f32_16x16x32_bf16(qf0, b0, sc, 0, 0, 0);
            sc = __builtin_amdgcn_mfma_f32_16x16x32_bf16(qf1, b1, sc, 0, 0, 0);
            s[c] = sc;
        }

#pragma unroll
        for (int r = 0; r < 4; ++r) {
            int qr = q0 + wave * 16 + quad * 4 + r;
            float mx = NEG_SENT;
#pragma unroll
            for (int c = 0; c < 2; ++c) {
                int kvi = kv0 + c * 16 + l15;
                float val = (kvi > qr) ? NEG_SENT : s[c][r] * 0.125f;  // causal, HD^-0.5
                s[c][r] = val;
                mx = fmaxf(mx, val);
            }
#pragma unroll
            for (int off = 8; off > 0; off >>= 1) mx = fmaxf(mx, __shfl_xor(mx, off, 16));
            float mn = fmaxf(m_r[r], mx);
            float alpha = expf(m_r[r] - mn);
            m_r[r] = mn;
            float ls = 0.f;
#pragma unroll
            for (int c = 0; c < 2; ++c) {
                float p = expf(s[c][r] - mn);
                s[c][r] = p;
                ls += p;
            }
#pragma unroll
            for (int off = 8; off > 0; off >>= 1) ls += __shfl_xor(ls, off, 16);
            l_r[r] = l_r[r] * alpha + ls;
#pragma unroll
            for (int d = 0; d < 4; ++d) oacc[d][r] *= alpha;
        }

        // P: C/D layout -> A-operand layout via LDS (per-wave region)
#pragma unroll
        for (int c = 0; c < 2; ++c)
#pragma unroll
            for (int r = 0; r < 4; ++r)
                Ps[wave][(quad * 4 + r) * 40 + c * 16 + l15] = f2s(s[c][r]);
        __syncthreads();

        short8 pf = *(const short8*)&Ps[wave][l15 * 40 + quad * 8];
#pragma unroll
        for (int d = 0; d < 4; ++d) {
            short8 vf = *(const short8*)&Vt[(d * 16 + l15) * 40 + quad * 8];
            oacc[d] = __builtin_amdgcn_mfma_f32_16x16x32_bf16(pf, vf, oacc[d], 0, 0, 0);
        }
        __syncthreads();
    }

    float linv[4];
#pragma unroll
    for (int r = 0; r < 4; ++r) linv[r] = (l_r[r] > 0.f) ? 1.f / l_r[r] : 0.f;
#pragma unroll
    for (int d = 0; d < 4; ++d)
#pragma unroll
        for (int r = 0; r < 4; ++r) {
            int qr = q0 + wave * 16 + quad * 4 + r;
            O[(size_t)(b * T_ + qr) * D_ + h * 64 + d * 16 + l15] = f2b(oacc[d][r] * linv[r]);
        }
}

// ---------------------------------------------------------------------------
// External tensors fp32; internals bf16. Workspace peak 40 MB:
//   Ah  [0,8)MB ; QL[8,16) KL[16,24) VL[24,32) AO[32,40)
//   MOD overlays [24,40) after attn+o-proj; M1G overlays [8,40) after modnorm.
//   X1 (fp32 residual stream) lives in d_out itself.
extern "C" void kernel_launch(void* const* d_in, const int* in_sizes, int n_in,
                              void* d_out, int out_size, void* d_ws, size_t ws_size,
                              hipStream_t stream) {
    const float* x     = (const float*)d_in[0];
    const float* acts  = (const float*)d_in[1];
    const float* n1_w  = (const float*)d_in[2];
    const float* n2_w  = (const float*)d_in[3];
    const float* q_w   = (const float*)d_in[4];
    const float* q_b   = (const float*)d_in[5];
    const float* k_w   = (const float*)d_in[6];
    const float* k_b   = (const float*)d_in[7];
    const float* v_w   = (const float*)d_in[8];
    const float* v_b   = (const float*)d_in[9];
    const float* qn_w  = (const float*)d_in[10];
    const float* kn_w  = (const float*)d_in[11];
    const float* o_w   = (const float*)d_in[12];
    const float* o_b   = (const float*)d_in[13];
    const float* ae1_w = (const float*)d_in[14];
    const float* ae1_b = (const float*)d_in[15];
    const float* ae2_w = (const float*)d_in[16];
    const float* ae2_b = (const float*)d_in[17];
    const float* mod_w = (const float*)d_in[18];
    const float* mod_b = (const float*)d_in[19];
    const float* m1_w  = (const float*)d_in[20];
    const float* m1_b  = (const float*)d_in[21];
    const float* m2_w  = (const float*)d_in[22];
    const float* m2_b  = (const float*)d_in[23];
    float* out = (float*)d_out;

    char* ws = (char*)d_ws;
    const size_t MB = 1ull << 20;
    bf16* Ah  = (bf16*)(ws + 0);
    bf16* QL  = (bf16*)(ws + 8 * MB);
    bf16* KL  = (bf16*)(ws + 16 * MB);
    bf16* VL  = (bf16*)(ws + 24 * MB);
    bf16* AO  = (bf16*)(ws + 32 * MB);
    bf16* MOD = (bf16*)(ws + 24 * MB);   // [NTOK,2048] overlays VL+AO
    bf16* M1G = (bf16*)(ws + 8 * MB);    // [NTOK,4096] overlays QL..AO/MOD
    bf16* AE1 = QL;
    bf16* AES = KL;
    float* X1 = out;                     // fp32 residual stream in d_out

    dim3 blk(256);
    dim3 g1k(8, 32);   // N=1024
    dim3 g2k(16, 32);  // N=2048
    dim3 g4k(32, 32);  // N=4096

    rmsnorm_k<<<NTOK, blk, 0, stream>>>(x, n1_w, Ah);
    gemm_k<0, float, bf16><<<g1k, blk, 0, stream>>>(Ah, q_w, q_b, (const float*)nullptr, QL, NTOK, 1024, 1024, 1024);
    gemm_k<0, float, bf16><<<g1k, blk, 0, stream>>>(Ah, k_w, k_b, (const float*)nullptr, KL, NTOK, 1024, 1024, 1024);
    gemm_k<0, float, bf16><<<g1k, blk, 0, stream>>>(Ah, v_w, v_b, (const float*)nullptr, VL, NTOK, 1024, 1024, 1024);
    qknorm_k<<<NTOK * 4, blk, 0, stream>>>(QL, KL, qn_w, kn_w);
    attn_k<<<dim3(T_ / 64, B_ * H_), blk, 0, stream>>>(QL, KL, VL, AO);
    gemm_k<0, float, float><<<g1k, blk, 0, stream>>>(AO, o_w, o_b, x, X1, NTOK, 1024, 1024, 1024);
    ae1_k<<<NTOK, blk, 0, stream>>>(acts, ae1_w, ae1_b, AE1);
    gemm_k<1, float, bf16><<<g1k, blk, 0, stream>>>(AE1, ae2_w, ae2_b, (const float*)nullptr, AES, NTOK, 1024, 1024, 1024);
    gemm_k<0, float, bf16><<<g2k, blk, 0, stream>>>(AES, mod_w, mod_b, (const float*)nullptr, MOD, NTOK, 2048, 1024, 4096);
    modnorm_k<<<NTOK, blk, 0, stream>>>(X1, MOD, n2_w, Ah);
    // m1_w is [K=1024, N=4096] -> row stride (ldw) = 4096, NOT 1024 (round-3 bug)
    gemm_k<2, float, bf16><<<g4k, blk, 0, stream>>>(Ah, m1_w, m1_b, (const float*)nullptr, M1G, NTOK, 4096, 1024, 4096);
    gemm_k<0, float, float><<<g1k, blk, 0, stream>>>(M1G, m2_w, m2_b, X1, out, NTOK, 1024, 4096, 1024);
}

// Round 5
// 696.124 us; speedup vs baseline: 1.8200x; 1.8200x over previous
//
#include <hip/hip_runtime.h>
#include <hip/hip_bf16.h>
#include <math.h>

typedef __hip_bfloat16 bf16;
typedef __attribute__((ext_vector_type(8))) short short8;
typedef __attribute__((ext_vector_type(4))) float float4_;

#define B_   2
#define T_   2048
#define D_   1024
#define H_   16
#define NTOK (B_ * T_)
#define NEG_SENT -1e30f

#define AS1 __attribute__((address_space(1)))
#define AS3 __attribute__((address_space(3)))

static __device__ __forceinline__ float b2f(bf16 v) { return __bfloat162float(v); }
static __device__ __forceinline__ bf16  f2b(float v) { return __float2bfloat16(v); }
static __device__ __forceinline__ short f2s(float v) {  // fp32 -> bf16 bits (RNE)
    unsigned u = __builtin_bit_cast(unsigned, v);
    unsigned r = (u + 0x7FFFu + ((u >> 16) & 1u)) >> 16;
    return (short)r;
}
static __device__ __forceinline__ float to_f(float v) { return v; }
static __device__ __forceinline__ float to_f(bf16 v) { return __bfloat162float(v); }
static __device__ __forceinline__ void  store_o(float* p, float v) { *p = v; }
static __device__ __forceinline__ void  store_o(bf16* p, float v) { *p = __float2bfloat16(v); }
// async global->LDS, 16B per lane; lds dest must be wave-uniform base (HW adds lane*16)
static __device__ __forceinline__ void gl_lds16(const void* g, void* l) {
    __builtin_amdgcn_global_load_lds((const AS1 unsigned int*)g, (AS3 unsigned int*)l, 16, 0, 0);
}

// ---------------- RMSNorm over D=1024 (one block per token), fp32 in, bf16 out
__global__ __launch_bounds__(256) void rmsnorm_k(const float* __restrict__ x,
                                                 const float* __restrict__ w,
                                                 bf16* __restrict__ out) {
    int t = blockIdx.x, tid = threadIdx.x;
    float xs[4], ss = 0.f;
#pragma unroll
    for (int i = 0; i < 4; ++i) {
        float v = x[(size_t)t * D_ + tid + i * 256];
        xs[i] = v; ss += v * v;
    }
    __shared__ float red[4];
#pragma unroll
    for (int off = 32; off > 0; off >>= 1) ss += __shfl_xor(ss, off, 64);
    if ((tid & 63) == 0) red[tid >> 6] = ss;
    __syncthreads();
    ss = red[0] + red[1] + red[2] + red[3];
    float inv = rsqrtf(ss * (1.f / D_) + 1e-6f);
#pragma unroll
    for (int i = 0; i < 4; ++i) {
        int c = tid + i * 256;
        out[(size_t)t * D_ + c] = f2b(xs[i] * inv * w[c]);
    }
}

// ------- fused modulate (x = x*(1+scale1)+shift1, in place fp32) + RMSNorm2 --
__global__ __launch_bounds__(256) void modnorm_k(float* __restrict__ x1,
                                                 const bf16* __restrict__ mod, // [NTOK][2048] = shift|scale
                                                 const float* __restrict__ w,
                                                 bf16* __restrict__ h2) {
    int t = blockIdx.x, tid = threadIdx.x;
    float xs[4], ss = 0.f;
#pragma unroll
    for (int i = 0; i < 4; ++i) {
        int c = tid + i * 256;
        float sh = b2f(mod[(size_t)t * 2048 + c]);
        float sc = b2f(mod[(size_t)t * 2048 + 1024 + c]);
        float v = x1[(size_t)t * D_ + c] * (1.f + sc) + sh;
        xs[i] = v; ss += v * v;
        x1[(size_t)t * D_ + c] = v;
    }
    __shared__ float red[4];
#pragma unroll
    for (int off = 32; off > 0; off >>= 1) ss += __shfl_xor(ss, off, 64);
    if ((tid & 63) == 0) red[tid >> 6] = ss;
    __syncthreads();
    ss = red[0] + red[1] + red[2] + red[3];
    float inv = rsqrtf(ss * (1.f / D_) + 1e-6f);
#pragma unroll
    for (int i = 0; i < 4; ++i) {
        int c = tid + i * 256;
        h2[(size_t)t * D_ + c] = f2b(xs[i] * inv * w[c]);
    }
}

// ------------- per-head RMSNorm for q and k, in place (HD=64, bf16 internal) -
__global__ __launch_bounds__(256) void qknorm_k(bf16* __restrict__ q, bf16* __restrict__ k,
                                                const float* __restrict__ qw,
                                                const float* __restrict__ kw) {
    int bid = blockIdx.x;
    int t = bid >> 2;
    int h = (bid & 3) * 4 + (threadIdx.x >> 6);
    int lane = threadIdx.x & 63;
    size_t idx = (size_t)t * D_ + h * 64 + lane;
    float qv = b2f(q[idx]);
    float ss = qv * qv;
#pragma unroll
    for (int off = 32; off > 0; off >>= 1) ss += __shfl_xor(ss, off, 64);
    q[idx] = f2b(qv * rsqrtf(ss * (1.f / 64.f) + 1e-6f) * qw[lane]);
    float kv = b2f(k[idx]);
    ss = kv * kv;
#pragma unroll
    for (int off = 32; off > 0; off >>= 1) ss += __shfl_xor(ss, off, 64);
    k[idx] = f2b(kv * rsqrtf(ss * (1.f / 64.f) + 1e-6f) * kw[lane]);
}

// ------------- ae1: [NTOK,16] @ [16,1024] + b, SiLU (fp32 in, bf16 out) -----
__global__ __launch_bounds__(256) void ae1_k(const float* __restrict__ actions,
                                             const float* __restrict__ w,
                                             const float* __restrict__ b,
                                             bf16* __restrict__ out) {
    int t = blockIdx.x, tid = threadIdx.x;
    float av[16];
#pragma unroll
    for (int a = 0; a < 16; ++a) av[a] = actions[(size_t)t * 16 + a];
#pragma unroll
    for (int i = 0; i < 4; ++i) {
        int n = tid + i * 256;
        float acc = b[n];
#pragma unroll
        for (int a = 0; a < 16; ++a) acc += av[a] * w[a * D_ + n];
        out[(size_t)t * D_ + n] = f2b(acc / (1.f + expf(-acc)));
    }
}

// ---- weight prep: fp32 W[K][N] (row stride ldw) -> bf16 WT[N][K], fused -----
struct WD { const float* src; bf16* dst; int K, N, ldw, tiles; };
struct WPack { WD d[8]; };
__global__ __launch_bounds__(256) void wprep_k(WPack p) {
    int bid = blockIdx.x;
    int mi = 0, cum = 0;
#pragma unroll
    for (mi = 0; mi < 8; ++mi) {
        if (bid < cum + p.d[mi].tiles) break;
        cum += p.d[mi].tiles;
    }
    if (mi >= 8) return;
    WD w = p.d[mi];
    int local = bid - cum;
    int tilesK = w.K >> 6;
    int tk = local % tilesK, tn = local / tilesK;
    int k0 = tk * 64, n0 = tn * 64;
    __shared__ short Tt[64 * 72];   // [n][k]
    int t = threadIdx.x;
    int row = t >> 2, seg = t & 3;
    const float* sp = w.src + (size_t)(k0 + row) * w.ldw + n0 + seg * 16;
#pragma unroll
    for (int q = 0; q < 4; ++q) {
        float4_ f = *(const float4_*)(sp + q * 4);
#pragma unroll
        for (int j = 0; j < 4; ++j) Tt[(seg * 16 + q * 4 + j) * 72 + row] = f2s(f[j]);
    }
    __syncthreads();
    bf16* dp = w.dst + (size_t)(n0 + row) * w.K + k0 + seg * 16;
    *(short8*)dp       = *(const short8*)&Tt[row * 72 + seg * 16];
    *(short8*)(dp + 8) = *(const short8*)&Tt[row * 72 + seg * 16 + 8];
}

// --------- MFMA GEMM (m97 structure): C = A[M,K](bf16) @ WT[N,K](bf16) -------
// ACT: 0 none, 1 SiLU, 2 GELU(exact). res (same [M,N]) added after ACT.
// A row stride K, Bt row stride K, out/res row stride N. M,N mult 128; K mult 64.
template <int ACT, typename ResT, typename OutT>
__global__ __launch_bounds__(256) void gemm_k(const bf16* __restrict__ A,
                                              const bf16* __restrict__ Bt,
                                              const float* __restrict__ bias,
                                              const ResT* __restrict__ res,
                                              OutT* __restrict__ out,
                                              int M, int N, int K) {
    __shared__ __align__(16) short As[128 * 64];   // [m][k], no pad (global_load_lds)
    __shared__ __align__(16) short Bs[128 * 64];   // [n][k]
    const int tid = threadIdx.x;
    const int bm = blockIdx.y * 128, bn = blockIdx.x * 128;
    const int wave = tid >> 6, lane = tid & 63;
    const int wm = (wave & 1) * 64, wn = (wave >> 1) * 64;
    const int l15 = lane & 15, quad = lane >> 4;
    const int lrow = lane >> 3, lseg = (lane & 7) * 8;
    float4_ acc[4][4] = {};

    for (int k0 = 0; k0 < K; k0 += 64) {
#pragma unroll
        for (int it = 0; it < 4; ++it) {           // 16B/lane async staging, both tiles
            int r = it * 32 + wave * 8;
            gl_lds16((const short*)A + (size_t)(bm + r + lrow) * K + k0 + lseg, &As[r * 64]);
            gl_lds16((const short*)Bt + (size_t)(bn + r + lrow) * K + k0 + lseg, &Bs[r * 64]);
        }
        __syncthreads();                            // drains vmcnt before barrier
#pragma unroll
        for (int kk = 0; kk < 64; kk += 32) {
            short8 af[4], bfr[4];
#pragma unroll
            for (int i = 0; i < 4; ++i)
                af[i] = *(const short8*)&As[(wm + i * 16 + l15) * 64 + kk + quad * 8];
#pragma unroll
            for (int j = 0; j < 4; ++j)
                bfr[j] = *(const short8*)&Bs[(wn + j * 16 + l15) * 64 + kk + quad * 8];
#pragma unroll
            for (int i = 0; i < 4; ++i)
#pragma unroll
                for (int j = 0; j < 4; ++j)
                    acc[i][j] = __builtin_amdgcn_mfma_f32_16x16x32_bf16(af[i], bfr[j], acc[i][j], 0, 0, 0);
        }
        __syncthreads();
    }

#pragma unroll
    for (int i = 0; i < 4; ++i) {
#pragma unroll
        for (int j = 0; j < 4; ++j) {
            int col = bn + wn + j * 16 + l15;
            float bv = bias[col];
#pragma unroll
            for (int r = 0; r < 4; ++r) {
                int row = bm + wm + i * 16 + quad * 4 + r;
                float v = acc[i][j][r] + bv;
                if (ACT == 1) v = v / (1.f + expf(-v));
                else if (ACT == 2) v = 0.5f * v * (1.f + erff(v * 0.70710678118654752f));
                if (res) v += to_f(res[(size_t)row * N + col]);
                store_o(&out[(size_t)row * N + col], v);
            }
        }
    }
}

// -------------- flash attention, causal, HD=64, MFMA 16x16x32 (bf16) --------
// grid: (T/64, B*H). block: 256 = 4 waves, each wave owns 16 q-rows.
// KV tile 64. K fragments direct from global (coalesced 16B/lane, no LDS).
// V^T double-buffered in LDS -> ONE barrier per KV tile. P via per-wave LDS
// (wave-synchronous DS ordering, no barrier needed).
__global__ __launch_bounds__(256) void attn_k(const bf16* __restrict__ Q,
                                              const bf16* __restrict__ Kg,
                                              const bf16* __restrict__ V,
                                              bf16* __restrict__ O) {
    __shared__ __align__(16) short Vt[2][64 * 72];  // [hd][kv]
    __shared__ __align__(16) short Ps[4][16 * 72];  // per-wave [q][kv]
    const int bh = blockIdx.y, b = bh >> 4, h = bh & 15;
    const int q0 = blockIdx.x * 64;
    const int tid = threadIdx.x, wave = tid >> 6, lane = tid & 63;
    const int l15 = lane & 15, quad = lane >> 4;
    const size_t base = (size_t)b * T_ * D_ + h * 64;

    const int qrow = q0 + wave * 16 + l15;
    short8 qf0 = *(const short8*)((const short*)Q + base + (size_t)qrow * D_ + quad * 8);
    short8 qf1 = *(const short8*)((const short*)Q + base + (size_t)qrow * D_ + 32 + quad * 8);

    float4_ oacc[4] = {};
    float m_r[4], l_r[4];
#pragma unroll
    for (int r = 0; r < 4; ++r) { m_r[r] = NEG_SENT; l_r[r] = 0.f; }

    const int vrow = tid >> 2, vseg = tid & 3;
    const int nit = q0 / 64 + 1;

    {   // stage V tile 0 (transposed) into buf 0
        const short* vp = (const short*)V + base + (size_t)vrow * D_ + vseg * 16;
        short8 v0 = *(const short8*)vp;
        short8 v1 = *(const short8*)(vp + 8);
#pragma unroll
        for (int j = 0; j < 8; ++j) Vt[0][(vseg * 16 + j) * 72 + vrow] = v0[j];
#pragma unroll
        for (int j = 0; j < 8; ++j) Vt[0][(vseg * 16 + 8 + j) * 72 + vrow] = v1[j];
    }
    __syncthreads();

    for (int it = 0; it < nit; ++it) {
        const int kv0 = it * 64, buf = it & 1;
        if (it + 1 < nit) {   // stage next V tile into other buffer (readers done pre-barrier)
            const short* vp = (const short*)V + base + (size_t)(kv0 + 64 + vrow) * D_ + vseg * 16;
            short8 v0 = *(const short8*)vp;
            short8 v1 = *(const short8*)(vp + 8);
#pragma unroll
            for (int j = 0; j < 8; ++j) Vt[buf ^ 1][(vseg * 16 + j) * 72 + vrow] = v0[j];
#pragma unroll
            for (int j = 0; j < 8; ++j) Vt[buf ^ 1][(vseg * 16 + 8 + j) * 72 + vrow] = v1[j];
        }

        // QK^T: K fragments straight from global (B-layout is coalesced 16B/lane)
        float4_ s[4];
#pragma unroll
        for (int c = 0; c < 4; ++c) {
            const short* kp = (const short*)Kg + base + (size_t)(kv0 + c * 16 + l15) * D_ + quad * 8;
            short8 kb0 = *(const short8*)kp;
            short8 kb1 = *(const short8*)(kp + 32);
            float4_ sc = {};
            sc = __builtin_amdgcn_mfma_f32_16x16x32_bf16(qf0, kb0, sc, 0, 0, 0);
            sc = __builtin_amdgcn_mfma_f32_16x16x32_bf16(qf1, kb1, sc, 0, 0, 0);
            s[c] = sc;
        }

#pragma unroll
        for (int r = 0; r < 4; ++r) {
            int qr = q0 + wave * 16 + quad * 4 + r;
            float mx = NEG_SENT;
#pragma unroll
            for (int c = 0; c < 4; ++c) {
                int kvi = kv0 + c * 16 + l15;
                float val = (kvi > qr) ? NEG_SENT : s[c][r] * 0.125f;  // causal, HD^-0.5
                s[c][r] = val;
                mx = fmaxf(mx, val);
            }
#pragma unroll
            for (int off = 8; off > 0; off >>= 1) mx = fmaxf(mx, __shfl_xor(mx, off, 16));
            float mn = fmaxf(m_r[r], mx);
            float alpha = expf(m_r[r] - mn);
            m_r[r] = mn;
            float ls = 0.f;
#pragma unroll
            for (int c = 0; c < 4; ++c) {
                float p = expf(s[c][r] - mn);
                s[c][r] = p;
                ls += p;
            }
#pragma unroll
            for (int off = 8; off > 0; off >>= 1) ls += __shfl_xor(ls, off, 16);
            l_r[r] = l_r[r] * alpha + ls;
#pragma unroll
            for (int d = 0; d < 4; ++d) oacc[d][r] *= alpha;
        }

        // P: C/D layout -> A-operand layout via per-wave LDS (no barrier: in-wave DS order)
#pragma unroll
        for (int c = 0; c < 4; ++c)
#pragma unroll
            for (int r = 0; r < 4; ++r)
                Ps[wave][(quad * 4 + r) * 72 + c * 16 + l15] = f2s(s[c][r]);

#pragma unroll
        for (int kk = 0; kk < 64; kk += 32) {
            short8 pf = *(const short8*)&Ps[wave][l15 * 72 + kk + quad * 8];
#pragma unroll
            for (int d = 0; d < 4; ++d) {
                short8 vf = *(const short8*)&Vt[buf][(d * 16 + l15) * 72 + kk + quad * 8];
                oacc[d] = __builtin_amdgcn_mfma_f32_16x16x32_bf16(pf, vf, oacc[d], 0, 0, 0);
            }
        }
        __syncthreads();   // single barrier per KV tile
    }

    float linv[4];
#pragma unroll
    for (int r = 0; r < 4; ++r) linv[r] = (l_r[r] > 0.f) ? 1.f / l_r[r] : 0.f;
#pragma unroll
    for (int d = 0; d < 4; ++d)
#pragma unroll
        for (int r = 0; r < 4; ++r) {
            int qr = q0 + wave * 16 + quad * 4 + r;
            O[(size_t)(b * T_ + qr) * D_ + h * 64 + d * 16 + l15] = f2b(oacc[d][r] * linv[r]);
        }
}

// ---------------------------------------------------------------------------
// External tensors fp32; internals bf16. Workspace peak 70 MB:
//   activations [0,40): Ah[0,8) QL[8,16) KL[16,24) VL[24,32) AO[32,40)
//     MOD overlays [24,40) after attn+o-proj; M1G overlays [8,40) after modnorm
//   bf16 W^T [40,70): q40 k42 v44 o46 ae2_48 mod50(4MB) m1_54(8MB) m2_62(8MB)
//   X1 (fp32 residual stream) lives in d_out itself.
extern "C" void kernel_launch(void* const* d_in, const int* in_sizes, int n_in,
                              void* d_out, int out_size, void* d_ws, size_t ws_size,
                              hipStream_t stream) {
    const float* x     = (const float*)d_in[0];
    const float* acts  = (const float*)d_in[1];
    const float* n1_w  = (const float*)d_in[2];
    const float* n2_w  = (const float*)d_in[3];
    const float* q_w   = (const float*)d_in[4];
    const float* q_b   = (const float*)d_in[5];
    const float* k_w   = (const float*)d_in[6];
    const float* k_b   = (const float*)d_in[7];
    const float* v_w   = (const float*)d_in[8];
    const float* v_b   = (const float*)d_in[9];
    const float* qn_w  = (const float*)d_in[10];
    const float* kn_w  = (const float*)d_in[11];
    const float* o_w   = (const float*)d_in[12];
    const float* o_b   = (const float*)d_in[13];
    const float* ae1_w = (const float*)d_in[14];
    const float* ae1_b = (const float*)d_in[15];
    const float* ae2_w = (const float*)d_in[16];
    const float* ae2_b = (const float*)d_in[17];
    const float* mod_w = (const float*)d_in[18];
    const float* mod_b = (const float*)d_in[19];
    const float* m1_w  = (const float*)d_in[20];
    const float* m1_b  = (const float*)d_in[21];
    const float* m2_w  = (const float*)d_in[22];
    const float* m2_b  = (const float*)d_in[23];
    float* out = (float*)d_out;

    char* ws = (char*)d_ws;
    const size_t MB = 1ull << 20;
    bf16* Ah  = (bf16*)(ws + 0);
    bf16* QL  = (bf16*)(ws + 8 * MB);
    bf16* KL  = (bf16*)(ws + 16 * MB);
    bf16* VL  = (bf16*)(ws + 24 * MB);
    bf16* AO  = (bf16*)(ws + 32 * MB);
    bf16* MOD = (bf16*)(ws + 24 * MB);   // [NTOK,2048] overlays VL+AO
    bf16* M1G = (bf16*)(ws + 8 * MB);    // [NTOK,4096] overlays QL..AO/MOD
    bf16* AE1 = QL;
    bf16* AES = KL;
    float* X1 = out;                     // fp32 residual stream in d_out

    bf16* WTq   = (bf16*)(ws + 40 * MB);
    bf16* WTk   = (bf16*)(ws + 42 * MB);
    bf16* WTv   = (bf16*)(ws + 44 * MB);
    bf16* WTo   = (bf16*)(ws + 46 * MB);
    bf16* WTae2 = (bf16*)(ws + 48 * MB);
    bf16* WTmod = (bf16*)(ws + 50 * MB); // [2048][1024]
    bf16* WTm1  = (bf16*)(ws + 54 * MB); // [4096][1024]
    bf16* WTm2  = (bf16*)(ws + 62 * MB); // [1024][4096]

    dim3 blk(256);
    dim3 g1k(8, 32);   // N=1024
    dim3 g2k(16, 32);  // N=2048
    dim3 g4k(32, 32);  // N=4096

    WPack p;
    p.d[0] = { q_w,   WTq,   1024, 1024, 1024, 256 };
    p.d[1] = { k_w,   WTk,   1024, 1024, 1024, 256 };
    p.d[2] = { v_w,   WTv,   1024, 1024, 1024, 256 };
    p.d[3] = { o_w,   WTo,   1024, 1024, 1024, 256 };
    p.d[4] = { ae2_w, WTae2, 1024, 1024, 1024, 256 };
    p.d[5] = { mod_w, WTmod, 1024, 2048, 4096, 512 };
    p.d[6] = { m1_w,  WTm1,  1024, 4096, 4096, 1024 };
    p.d[7] = { m2_w,  WTm2,  4096, 1024, 1024, 1024 };
    wprep_k<<<3840, blk, 0, stream>>>(p);

    rmsnorm_k<<<NTOK, blk, 0, stream>>>(x, n1_w, Ah);
    gemm_k<0, float, bf16><<<g1k, blk, 0, stream>>>(Ah, WTq, q_b, (const float*)nullptr, QL, NTOK, 1024, 1024);
    gemm_k<0, float, bf16><<<g1k, blk, 0, stream>>>(Ah, WTk, k_b, (const float*)nullptr, KL, NTOK, 1024, 1024);
    gemm_k<0, float, bf16><<<g1k, blk, 0, stream>>>(Ah, WTv, v_b, (const float*)nullptr, VL, NTOK, 1024, 1024);
    qknorm_k<<<NTOK * 4, blk, 0, stream>>>(QL, KL, qn_w, kn_w);
    attn_k<<<dim3(T_ / 64, B_ * H_), blk, 0, stream>>>(QL, KL, VL, AO);
    gemm_k<0, float, float><<<g1k, blk, 0, stream>>>(AO, WTo, o_b, x, X1, NTOK, 1024, 1024);
    ae1_k<<<NTOK, blk, 0, stream>>>(acts, ae1_w, ae1_b, AE1);
    gemm_k<1, float, bf16><<<g1k, blk, 0, stream>>>(AE1, WTae2, ae2_b, (const float*)nullptr, AES, NTOK, 1024, 1024);
    gemm_k<0, float, bf16><<<g2k, blk, 0, stream>>>(AES, WTmod, mod_b, (const float*)nullptr, MOD, NTOK, 2048, 1024);
    modnorm_k<<<NTOK, blk, 0, stream>>>(X1, MOD, n2_w, Ah);
    gemm_k<2, float, bf16><<<g4k, blk, 0, stream>>>(Ah, WTm1, m1_b, (const float*)nullptr, M1G, NTOK, 4096, 1024);
    gemm_k<0, float, float><<<g1k, blk, 0, stream>>>(M1G, WTm2, m2_b, X1, out, NTOK, 1024, 4096);
}

// Round 6
// 665.996 us; speedup vs baseline: 1.9024x; 1.0452x over previous
//
#include <hip/hip_runtime.h>
#include <hip/hip_bf16.h>
#include <math.h>

typedef __hip_bfloat16 bf16;
typedef __attribute__((ext_vector_type(8))) short short8;
typedef __attribute__((ext_vector_type(4))) float float4_;

#define B_   2
#define T_   2048
#define D_   1024
#define H_   16
#define NTOK (B_ * T_)
#define NEG_SENT -1e30f

#define AS1 __attribute__((address_space(1)))
#define AS3 __attribute__((address_space(3)))

static __device__ __forceinline__ float b2f(bf16 v) { return __bfloat162float(v); }
static __device__ __forceinline__ bf16  f2b(float v) { return __float2bfloat16(v); }
static __device__ __forceinline__ short f2s(float v) {  // fp32 -> bf16 bits (RNE)
    unsigned u = __builtin_bit_cast(unsigned, v);
    unsigned r = (u + 0x7FFFu + ((u >> 16) & 1u)) >> 16;
    return (short)r;
}
static __device__ __forceinline__ float to_f(float v) { return v; }
static __device__ __forceinline__ float to_f(bf16 v) { return __bfloat162float(v); }
static __device__ __forceinline__ void  store_o(float* p, float v) { *p = v; }
static __device__ __forceinline__ void  store_o(bf16* p, float v) { *p = __float2bfloat16(v); }
static __device__ __forceinline__ void gl_lds16(const void* g, void* l) {
    __builtin_amdgcn_global_load_lds((const AS1 unsigned int*)g, (AS3 unsigned int*)l, 16, 0, 0);
}

// ---------------- RMSNorm over D=1024 (one block per token), fp32 in, bf16 out
__global__ __launch_bounds__(256) void rmsnorm_k(const float* __restrict__ x,
                                                 const float* __restrict__ w,
                                                 bf16* __restrict__ out) {
    int t = blockIdx.x, tid = threadIdx.x;
    float xs[4], ss = 0.f;
#pragma unroll
    for (int i = 0; i < 4; ++i) {
        float v = x[(size_t)t * D_ + tid + i * 256];
        xs[i] = v; ss += v * v;
    }
    __shared__ float red[4];
#pragma unroll
    for (int off = 32; off > 0; off >>= 1) ss += __shfl_xor(ss, off, 64);
    if ((tid & 63) == 0) red[tid >> 6] = ss;
    __syncthreads();
    ss = red[0] + red[1] + red[2] + red[3];
    float inv = rsqrtf(ss * (1.f / D_) + 1e-6f);
#pragma unroll
    for (int i = 0; i < 4; ++i) {
        int c = tid + i * 256;
        out[(size_t)t * D_ + c] = f2b(xs[i] * inv * w[c]);
    }
}

// ------- fused modulate (x = x*(1+scale1)+shift1, in place fp32) + RMSNorm2 --
__global__ __launch_bounds__(256) void modnorm_k(float* __restrict__ x1,
                                                 const bf16* __restrict__ mod, // [NTOK][2048] = shift|scale
                                                 const float* __restrict__ w,
                                                 bf16* __restrict__ h2) {
    int t = blockIdx.x, tid = threadIdx.x;
    float xs[4], ss = 0.f;
#pragma unroll
    for (int i = 0; i < 4; ++i) {
        int c = tid + i * 256;
        float sh = b2f(mod[(size_t)t * 2048 + c]);
        float sc = b2f(mod[(size_t)t * 2048 + 1024 + c]);
        float v = x1[(size_t)t * D_ + c] * (1.f + sc) + sh;
        xs[i] = v; ss += v * v;
        x1[(size_t)t * D_ + c] = v;
    }
    __shared__ float red[4];
#pragma unroll
    for (int off = 32; off > 0; off >>= 1) ss += __shfl_xor(ss, off, 64);
    if ((tid & 63) == 0) red[tid >> 6] = ss;
    __syncthreads();
    ss = red[0] + red[1] + red[2] + red[3];
    float inv = rsqrtf(ss * (1.f / D_) + 1e-6f);
#pragma unroll
    for (int i = 0; i < 4; ++i) {
        int c = tid + i * 256;
        h2[(size_t)t * D_ + c] = f2b(xs[i] * inv * w[c]);
    }
}

// ---- per-head RMSNorm for q and k in the packed QKV [NTOK][3072], in place --
__global__ __launch_bounds__(256) void qknorm_k(bf16* __restrict__ qkv,
                                                const float* __restrict__ qw,
                                                const float* __restrict__ kw) {
    int bid = blockIdx.x;
    int t = bid >> 2;
    int h = (bid & 3) * 4 + (threadIdx.x >> 6);
    int lane = threadIdx.x & 63;
    size_t qi = (size_t)t * 3072 + h * 64 + lane;
    size_t ki = qi + 1024;
    float qv = b2f(qkv[qi]);
    float ss = qv * qv;
#pragma unroll
    for (int off = 32; off > 0; off >>= 1) ss += __shfl_xor(ss, off, 64);
    qkv[qi] = f2b(qv * rsqrtf(ss * (1.f / 64.f) + 1e-6f) * qw[lane]);
    float kv = b2f(qkv[ki]);
    ss = kv * kv;
#pragma unroll
    for (int off = 32; off > 0; off >>= 1) ss += __shfl_xor(ss, off, 64);
    qkv[ki] = f2b(kv * rsqrtf(ss * (1.f / 64.f) + 1e-6f) * kw[lane]);
}

// ------------- ae1: [NTOK,16] @ [16,1024] + b, SiLU (fp32 in, bf16 out) -----
__global__ __launch_bounds__(256) void ae1_k(const float* __restrict__ actions,
                                             const float* __restrict__ w,
                                             const float* __restrict__ b,
                                             bf16* __restrict__ out) {
    int t = blockIdx.x, tid = threadIdx.x;
    float av[16];
#pragma unroll
    for (int a = 0; a < 16; ++a) av[a] = actions[(size_t)t * 16 + a];
#pragma unroll
    for (int i = 0; i < 4; ++i) {
        int n = tid + i * 256;
        float acc = b[n];
#pragma unroll
        for (int a = 0; a < 16; ++a) acc += av[a] * w[a * D_ + n];
        out[(size_t)t * D_ + n] = f2b(acc / (1.f + expf(-acc)));
    }
}

// ---- weight prep: fp32 W[K][N] (row stride ldw) -> bf16 WT[N][K], fused -----
struct WD { const float* src; bf16* dst; int K, N, ldw, tiles; };
struct WPack { WD d[8]; };
__global__ __launch_bounds__(256) void wprep_k(WPack p) {
    int bid = blockIdx.x;
    int mi = 0, cum = 0;
#pragma unroll
    for (mi = 0; mi < 8; ++mi) {
        if (bid < cum + p.d[mi].tiles) break;
        cum += p.d[mi].tiles;
    }
    if (mi >= 8) return;
    WD w = p.d[mi];
    int local = bid - cum;
    int tilesK = w.K >> 6;
    int tk = local % tilesK, tn = local / tilesK;
    int k0 = tk * 64, n0 = tn * 64;
    __shared__ short Tt[64 * 72];   // [n][k]
    int t = threadIdx.x;
    int row = t >> 2, seg = t & 3;
    const float* sp = w.src + (size_t)(k0 + row) * w.ldw + n0 + seg * 16;
#pragma unroll
    for (int q = 0; q < 4; ++q) {
        float4_ f = *(const float4_*)(sp + q * 4);
#pragma unroll
        for (int j = 0; j < 4; ++j) Tt[(seg * 16 + q * 4 + j) * 72 + row] = f2s(f[j]);
    }
    __syncthreads();
    bf16* dp = w.dst + (size_t)(n0 + row) * w.K + k0 + seg * 16;
    *(short8*)dp       = *(const short8*)&Tt[row * 72 + seg * 16];
    *(short8*)(dp + 8) = *(const short8*)&Tt[row * 72 + seg * 16 + 8];
}

// ---- concat q_b|k_b|v_b -> biasQKV[3072] ------------------------------------
__global__ __launch_bounds__(256) void bcat_k(const float* __restrict__ qb,
                                              const float* __restrict__ kb,
                                              const float* __restrict__ vb,
                                              float* __restrict__ dst) {
    int i = blockIdx.x * 256 + threadIdx.x;   // grid 12*256 = 3072
    const float* s = (i < 1024) ? qb : (i < 2048) ? kb : vb;
    dst[i] = s[i & 1023];
}

// --------- MFMA GEMM 128x128: C = A[M,K](bf16) @ WT[N,K](bf16) ---------------
// ACT: 0 none, 1 SiLU, 2 GELU(exact). res added after ACT. ldo = out/res stride.
template <int ACT, typename ResT, typename OutT>
__global__ __launch_bounds__(256) void gemm_k(const bf16* __restrict__ A,
                                              const bf16* __restrict__ Bt,
                                              const float* __restrict__ bias,
                                              const ResT* __restrict__ res,
                                              OutT* __restrict__ out,
                                              int M, int N, int K, int ldo) {
    __shared__ __align__(16) short As[128 * 64];
    __shared__ __align__(16) short Bs[128 * 64];
    const int tid = threadIdx.x;
    const int bm = blockIdx.y * 128, bn = blockIdx.x * 128;
    const int wave = tid >> 6, lane = tid & 63;
    const int wm = (wave & 1) * 64, wn = (wave >> 1) * 64;
    const int l15 = lane & 15, quad = lane >> 4;
    const int lrow = lane >> 3, lseg = (lane & 7) * 8;
    float4_ acc[4][4] = {};

    for (int k0 = 0; k0 < K; k0 += 64) {
#pragma unroll
        for (int it = 0; it < 4; ++it) {
            int r = it * 32 + wave * 8;
            gl_lds16((const short*)A + (size_t)(bm + r + lrow) * K + k0 + lseg, &As[r * 64]);
            gl_lds16((const short*)Bt + (size_t)(bn + r + lrow) * K + k0 + lseg, &Bs[r * 64]);
        }
        __syncthreads();
#pragma unroll
        for (int kk = 0; kk < 64; kk += 32) {
            short8 af[4], bfr[4];
#pragma unroll
            for (int i = 0; i < 4; ++i)
                af[i] = *(const short8*)&As[(wm + i * 16 + l15) * 64 + kk + quad * 8];
#pragma unroll
            for (int j = 0; j < 4; ++j)
                bfr[j] = *(const short8*)&Bs[(wn + j * 16 + l15) * 64 + kk + quad * 8];
#pragma unroll
            for (int i = 0; i < 4; ++i)
#pragma unroll
                for (int j = 0; j < 4; ++j)
                    acc[i][j] = __builtin_amdgcn_mfma_f32_16x16x32_bf16(af[i], bfr[j], acc[i][j], 0, 0, 0);
        }
        __syncthreads();
    }

#pragma unroll
    for (int i = 0; i < 4; ++i)
#pragma unroll
        for (int j = 0; j < 4; ++j) {
            int col = bn + wn + j * 16 + l15;
            float bv = bias[col];
#pragma unroll
            for (int r = 0; r < 4; ++r) {
                int row = bm + wm + i * 16 + quad * 4 + r;
                float v = acc[i][j][r] + bv;
                if (ACT == 1) v = v / (1.f + expf(-v));
                else if (ACT == 2) v = 0.5f * v * (1.f + erff(v * 0.70710678118654752f));
                if (res) v += to_f(res[(size_t)row * ldo + col]);
                store_o(&out[(size_t)row * ldo + col], v);
            }
        }
}

// --------- MFMA GEMM 64x128 tile: for N=1024 GEMMs (512 blocks = 2/CU) -------
template <int ACT, typename ResT, typename OutT>
__global__ __launch_bounds__(256) void gemm64_k(const bf16* __restrict__ A,
                                                const bf16* __restrict__ Bt,
                                                const float* __restrict__ bias,
                                                const ResT* __restrict__ res,
                                                OutT* __restrict__ out,
                                                int M, int N, int K) {
    __shared__ __align__(16) short As[64 * 64];
    __shared__ __align__(16) short Bs[128 * 64];
    const int tid = threadIdx.x;
    const int bm = blockIdx.y * 64, bn = blockIdx.x * 128;
    const int wave = tid >> 6, lane = tid & 63;
    const int wm = (wave & 1) * 32, wn = (wave >> 1) * 64;
    const int l15 = lane & 15, quad = lane >> 4;
    const int lrow = lane >> 3, lseg = (lane & 7) * 8;
    float4_ acc[2][4] = {};

    for (int k0 = 0; k0 < K; k0 += 64) {
#pragma unroll
        for (int it = 0; it < 2; ++it) {
            int r = wave * 16 + it * 8;
            gl_lds16((const short*)A + (size_t)(bm + r + lrow) * K + k0 + lseg, &As[r * 64]);
        }
#pragma unroll
        for (int it = 0; it < 4; ++it) {
            int r = it * 32 + wave * 8;
            gl_lds16((const short*)Bt + (size_t)(bn + r + lrow) * K + k0 + lseg, &Bs[r * 64]);
        }
        __syncthreads();
#pragma unroll
        for (int kk = 0; kk < 64; kk += 32) {
            short8 af[2], bfr[4];
#pragma unroll
            for (int i = 0; i < 2; ++i)
                af[i] = *(const short8*)&As[(wm + i * 16 + l15) * 64 + kk + quad * 8];
#pragma unroll
            for (int j = 0; j < 4; ++j)
                bfr[j] = *(const short8*)&Bs[(wn + j * 16 + l15) * 64 + kk + quad * 8];
#pragma unroll
            for (int i = 0; i < 2; ++i)
#pragma unroll
                for (int j = 0; j < 4; ++j)
                    acc[i][j] = __builtin_amdgcn_mfma_f32_16x16x32_bf16(af[i], bfr[j], acc[i][j], 0, 0, 0);
        }
        __syncthreads();
    }

#pragma unroll
    for (int i = 0; i < 2; ++i)
#pragma unroll
        for (int j = 0; j < 4; ++j) {
            int col = bn + wn + j * 16 + l15;
            float bv = bias[col];
#pragma unroll
            for (int r = 0; r < 4; ++r) {
                int row = bm + wm + i * 16 + quad * 4 + r;
                float v = acc[i][j][r] + bv;
                if (ACT == 1) v = v / (1.f + expf(-v));
                else if (ACT == 2) v = 0.5f * v * (1.f + erff(v * 0.70710678118654752f));
                if (res) v += to_f(res[(size_t)row * N + col]);
                store_o(&out[(size_t)row * N + col], v);
            }
        }
}

// -------------- flash attention, causal, HD=64, q-tile 128, KV tile 64 -------
// grid: (T/128, B*H), LPT order (bx=0 -> longest block). block 256 = 4 waves;
// each wave owns 2 groups of 16 q-rows -> K fragments reused 2x.
// QKV packed [NTOK][3072]; O [NTOK][1024].
__global__ __launch_bounds__(256) void attn_k(const bf16* __restrict__ QKV,
                                              bf16* __restrict__ O) {
    __shared__ __align__(16) short Vt[2][64 * 72];   // [hd][kv]
    __shared__ __align__(16) short Ps[4][2][16 * 72];
    const int bh = blockIdx.y, b = bh >> 4, h = bh & 15;
    const int qb = T_ - 128 * (blockIdx.x + 1);      // longest-first
    const int tid = threadIdx.x, wave = tid >> 6, lane = tid & 63;
    const int l15 = lane & 15, quad = lane >> 4;
    const size_t base = (size_t)b * T_ * 3072 + h * 64;
    const short* Qp = (const short*)QKV + base;
    const short* Kp = Qp + 1024;
    const short* Vp = Qp + 2048;

    short8 qf[2][2];
#pragma unroll
    for (int g = 0; g < 2; ++g) {
        int qrow = qb + g * 64 + wave * 16 + l15;
        qf[g][0] = *(const short8*)(Qp + (size_t)qrow * 3072 + quad * 8);
        qf[g][1] = *(const short8*)(Qp + (size_t)qrow * 3072 + 32 + quad * 8);
    }

    float4_ oacc[2][4] = {};
    float m_r[2][4], l_r[2][4];
#pragma unroll
    for (int g = 0; g < 2; ++g)
#pragma unroll
        for (int r = 0; r < 4; ++r) { m_r[g][r] = NEG_SENT; l_r[g][r] = 0.f; }

    const int vrow = tid >> 2, vseg = tid & 3;
    const int nit = qb / 64 + 2;

    {   // stage V tile 0 (transposed) into buf 0
        const short* vp = Vp + (size_t)vrow * 3072 + vseg * 16;
        short8 v0 = *(const short8*)vp;
        short8 v1 = *(const short8*)(vp + 8);
#pragma unroll
        for (int j = 0; j < 8; ++j) Vt[0][(vseg * 16 + j) * 72 + vrow] = v0[j];
#pragma unroll
        for (int j = 0; j < 8; ++j) Vt[0][(vseg * 16 + 8 + j) * 72 + vrow] = v1[j];
    }
    __syncthreads();

    for (int it = 0; it < nit; ++it) {
        const int kv0 = it * 64, buf = it & 1;
        if (it + 1 < nit) {
            const short* vp = Vp + (size_t)(kv0 + 64 + vrow) * 3072 + vseg * 16;
            short8 v0 = *(const short8*)vp;
            short8 v1 = *(const short8*)(vp + 8);
#pragma unroll
            for (int j = 0; j < 8; ++j) Vt[buf ^ 1][(vseg * 16 + j) * 72 + vrow] = v0[j];
#pragma unroll
            for (int j = 0; j < 8; ++j) Vt[buf ^ 1][(vseg * 16 + 8 + j) * 72 + vrow] = v1[j];
        }

        // QK^T: K fragment loaded once, used for both q-row groups
        float4_ s[2][4];
#pragma unroll
        for (int c = 0; c < 4; ++c) {
            const short* kp = Kp + (size_t)(kv0 + c * 16 + l15) * 3072 + quad * 8;
            short8 kb0 = *(const short8*)kp;
            short8 kb1 = *(const short8*)(kp + 32);
#pragma unroll
            for (int g = 0; g < 2; ++g) {
                float4_ sc = {};
                sc = __builtin_amdgcn_mfma_f32_16x16x32_bf16(qf[g][0], kb0, sc, 0, 0, 0);
                sc = __builtin_amdgcn_mfma_f32_16x16x32_bf16(qf[g][1], kb1, sc, 0, 0, 0);
                s[g][c] = sc;
            }
        }

#pragma unroll
        for (int g = 0; g < 2; ++g) {
            bool active = !(g == 0 && kv0 >= qb + 64);   // g0's last tile fully masked
            if (active) {
#pragma unroll
                for (int r = 0; r < 4; ++r) {
                    int qr = qb + g * 64 + wave * 16 + quad * 4 + r;
                    float mx = NEG_SENT;
#pragma unroll
                    for (int c = 0; c < 4; ++c) {
                        int kvi = kv0 + c * 16 + l15;
                        float val = (kvi > qr) ? NEG_SENT : s[g][c][r] * 0.125f;
                        s[g][c][r] = val;
                        mx = fmaxf(mx, val);
                    }
#pragma unroll
                    for (int off = 8; off > 0; off >>= 1) mx = fmaxf(mx, __shfl_xor(mx, off, 16));
                    float mn = fmaxf(m_r[g][r], mx);
                    float alpha = expf(m_r[g][r] - mn);
                    m_r[g][r] = mn;
                    float ls = 0.f;
#pragma unroll
                    for (int c = 0; c < 4; ++c) {
                        float p = expf(s[g][c][r] - mn);
                        s[g][c][r] = p;
                        ls += p;
                    }
#pragma unroll
                    for (int off = 8; off > 0; off >>= 1) ls += __shfl_xor(ls, off, 16);
                    l_r[g][r] = l_r[g][r] * alpha + ls;
#pragma unroll
                    for (int d = 0; d < 4; ++d) oacc[g][d][r] *= alpha;
                }

                // P: C/D -> A layout via per-wave LDS (wave-synchronous, no barrier)
#pragma unroll
                for (int c = 0; c < 4; ++c)
#pragma unroll
                    for (int r = 0; r < 4; ++r)
                        Ps[wave][g][(quad * 4 + r) * 72 + c * 16 + l15] = f2s(s[g][c][r]);

#pragma unroll
                for (int kk = 0; kk < 64; kk += 32) {
                    short8 pf = *(const short8*)&Ps[wave][g][l15 * 72 + kk + quad * 8];
#pragma unroll
                    for (int d = 0; d < 4; ++d) {
                        short8 vf = *(const short8*)&Vt[buf][(d * 16 + l15) * 72 + kk + quad * 8];
                        oacc[g][d] = __builtin_amdgcn_mfma_f32_16x16x32_bf16(pf, vf, oacc[g][d], 0, 0, 0);
                    }
                }
            }
        }
        __syncthreads();   // single barrier per KV tile
    }

#pragma unroll
    for (int g = 0; g < 2; ++g) {
        float linv[4];
#pragma unroll
        for (int r = 0; r < 4; ++r) linv[r] = (l_r[g][r] > 0.f) ? 1.f / l_r[g][r] : 0.f;
#pragma unroll
        for (int d = 0; d < 4; ++d)
#pragma unroll
            for (int r = 0; r < 4; ++r) {
                int qr = qb + g * 64 + wave * 16 + quad * 4 + r;
                O[(size_t)(b * T_ + qr) * D_ + h * 64 + d * 16 + l15] = f2b(oacc[g][d][r] * linv[r]);
            }
    }
}

// ---------------------------------------------------------------------------
// Workspace (~70.1 MB):
//   Ah[0,8) ; QKVp[8,32) ([NTOK][3072] bf16) ; AO[32,40)
//   after attn+o-proj: AE1[8,16) AES[16,24) MOD[24,40) ; M1G[8,40) after modnorm
//   weights [40,70): WTqkv 40 (6MB contig) WTo 46 WTae2 48 WTmod 50 WTm1 54 WTm2 62
//   biasQKV at 70MB. X1 (fp32 residual) lives in d_out.
extern "C" void kernel_launch(void* const* d_in, const int* in_sizes, int n_in,
                              void* d_out, int out_size, void* d_ws, size_t ws_size,
                              hipStream_t stream) {
    const float* x     = (const float*)d_in[0];
    const float* acts  = (const float*)d_in[1];
    const float* n1_w  = (const float*)d_in[2];
    const float* n2_w  = (const float*)d_in[3];
    const float* q_w   = (const float*)d_in[4];
    const float* q_b   = (const float*)d_in[5];
    const float* k_w   = (const float*)d_in[6];
    const float* k_b   = (const float*)d_in[7];
    const float* v_w   = (const float*)d_in[8];
    const float* v_b   = (const float*)d_in[9];
    const float* qn_w  = (const float*)d_in[10];
    const float* kn_w  = (const float*)d_in[11];
    const float* o_w   = (const float*)d_in[12];
    const float* o_b   = (const float*)d_in[13];
    const float* ae1_w = (const float*)d_in[14];
    const float* ae1_b = (const float*)d_in[15];
    const float* ae2_w = (const float*)d_in[16];
    const float* ae2_b = (const float*)d_in[17];
    const float* mod_w = (const float*)d_in[18];
    const float* mod_b = (const float*)d_in[19];
    const float* m1_w  = (const float*)d_in[20];
    const float* m1_b  = (const float*)d_in[21];
    const float* m2_w  = (const float*)d_in[22];
    const float* m2_b  = (const float*)d_in[23];
    float* out = (float*)d_out;

    char* ws = (char*)d_ws;
    const size_t MB = 1ull << 20;
    bf16*  Ah   = (bf16*)(ws + 0);
    bf16*  QKVp = (bf16*)(ws + 8 * MB);    // [NTOK][3072]
    bf16*  AO   = (bf16*)(ws + 32 * MB);
    bf16*  AE1  = (bf16*)(ws + 8 * MB);
    bf16*  AES  = (bf16*)(ws + 16 * MB);
    bf16*  MOD  = (bf16*)(ws + 24 * MB);
    bf16*  M1G  = (bf16*)(ws + 8 * MB);
    float* X1   = out;

    bf16* WTqkv = (bf16*)(ws + 40 * MB);   // q|k|v contiguous -> [3072][1024]
    bf16* WTo   = (bf16*)(ws + 46 * MB);
    bf16* WTae2 = (bf16*)(ws + 48 * MB);
    bf16* WTmod = (bf16*)(ws + 50 * MB);   // [2048][1024]
    bf16* WTm1  = (bf16*)(ws + 54 * MB);   // [4096][1024]
    bf16* WTm2  = (bf16*)(ws + 62 * MB);   // [1024][4096]
    float* biasQKV = (float*)(ws + 70 * MB);

    dim3 blk(256);

    WPack p;
    p.d[0] = { q_w,   WTqkv,                1024, 1024, 1024, 256 };
    p.d[1] = { k_w,   WTqkv + 1024 * 1024,  1024, 1024, 1024, 256 };
    p.d[2] = { v_w,   WTqkv + 2048 * 1024,  1024, 1024, 1024, 256 };
    p.d[3] = { o_w,   WTo,   1024, 1024, 1024, 256 };
    p.d[4] = { ae2_w, WTae2, 1024, 1024, 1024, 256 };
    p.d[5] = { mod_w, WTmod, 1024, 2048, 4096, 512 };
    p.d[6] = { m1_w,  WTm1,  1024, 4096, 4096, 1024 };
    p.d[7] = { m2_w,  WTm2,  4096, 1024, 1024, 1024 };
    wprep_k<<<3840, blk, 0, stream>>>(p);
    bcat_k<<<12, blk, 0, stream>>>(q_b, k_b, v_b, biasQKV);

    rmsnorm_k<<<NTOK, blk, 0, stream>>>(x, n1_w, Ah);
    gemm_k<0, float, bf16><<<dim3(24, 32), blk, 0, stream>>>(Ah, WTqkv, biasQKV, (const float*)nullptr, QKVp, NTOK, 3072, 1024, 3072);
    qknorm_k<<<NTOK * 4, blk, 0, stream>>>(QKVp, qn_w, kn_w);
    attn_k<<<dim3(T_ / 128, B_ * H_), blk, 0, stream>>>(QKVp, AO);
    gemm64_k<0, float, float><<<dim3(8, 64), blk, 0, stream>>>(AO, WTo, o_b, x, X1, NTOK, 1024, 1024);
    ae1_k<<<NTOK, blk, 0, stream>>>(acts, ae1_w, ae1_b, AE1);
    gemm64_k<1, float, bf16><<<dim3(8, 64), blk, 0, stream>>>(AE1, WTae2, ae2_b, (const float*)nullptr, AES, NTOK, 1024, 1024);
    gemm_k<0, float, bf16><<<dim3(16, 32), blk, 0, stream>>>(AES, WTmod, mod_b, (const float*)nullptr, MOD, NTOK, 2048, 1024, 2048);
    modnorm_k<<<NTOK, blk, 0, stream>>>(X1, MOD, n2_w, Ah);
    gemm_k<2, float, bf16><<<dim3(32, 32), blk, 0, stream>>>(Ah, WTm1, m1_b, (const float*)nullptr, M1G, NTOK, 4096, 1024, 4096);
    gemm64_k<0, float, float><<<dim3(8, 64), blk, 0, stream>>>(M1G, WTm2, m2_b, X1, out, NTOK, 1024, 4096);
}

// Round 7
// 594.114 us; speedup vs baseline: 2.1325x; 1.1210x over previous
//
#include <hip/hip_runtime.h>
#include <hip/hip_bf16.h>
#include <math.h>

typedef __hip_bfloat16 bf16;
typedef __attribute__((ext_vector_type(8))) short short8;
typedef __attribute__((ext_vector_type(4))) float float4_;

#define B_   2
#define T_   2048
#define D_   1024
#define H_   16
#define NTOK (B_ * T_)
#define NEG_SENT -1e30f

#define AS1 __attribute__((address_space(1)))
#define AS3 __attribute__((address_space(3)))

static __device__ __forceinline__ float b2f(bf16 v) { return __bfloat162float(v); }
static __device__ __forceinline__ bf16  f2b(float v) { return __float2bfloat16(v); }
static __device__ __forceinline__ short f2s(float v) {  // fp32 -> bf16 bits (RNE)
    unsigned u = __builtin_bit_cast(unsigned, v);
    unsigned r = (u + 0x7FFFu + ((u >> 16) & 1u)) >> 16;
    return (short)r;
}
static __device__ __forceinline__ float to_f(float v) { return v; }
static __device__ __forceinline__ float to_f(bf16 v) { return __bfloat162float(v); }
static __device__ __forceinline__ void  store_o(float* p, float v) { *p = v; }
static __device__ __forceinline__ void  store_o(bf16* p, float v) { *p = __float2bfloat16(v); }
static __device__ __forceinline__ void gl_lds16(const void* g, void* l) {
    __builtin_amdgcn_global_load_lds((const AS1 unsigned int*)g, (AS3 unsigned int*)l, 16, 0, 0);
}

// ---------------- RMSNorm over D=1024 (one block per token), fp32 in, bf16 out
__global__ __launch_bounds__(256) void rmsnorm_k(const float* __restrict__ x,
                                                 const float* __restrict__ w,
                                                 bf16* __restrict__ out) {
    int t = blockIdx.x, tid = threadIdx.x;
    float xs[4], ss = 0.f;
#pragma unroll
    for (int i = 0; i < 4; ++i) {
        float v = x[(size_t)t * D_ + tid + i * 256];
        xs[i] = v; ss += v * v;
    }
    __shared__ float red[4];
#pragma unroll
    for (int off = 32; off > 0; off >>= 1) ss += __shfl_xor(ss, off, 64);
    if ((tid & 63) == 0) red[tid >> 6] = ss;
    __syncthreads();
    ss = red[0] + red[1] + red[2] + red[3];
    float inv = rsqrtf(ss * (1.f / D_) + 1e-6f);
#pragma unroll
    for (int i = 0; i < 4; ++i) {
        int c = tid + i * 256;
        out[(size_t)t * D_ + c] = f2b(xs[i] * inv * w[c]);
    }
}

// ------- fused modulate (x = x*(1+scale1)+shift1, in place fp32) + RMSNorm2 --
__global__ __launch_bounds__(256) void modnorm_k(float* __restrict__ x1,
                                                 const bf16* __restrict__ mod, // [NTOK][2048] = shift|scale
                                                 const float* __restrict__ w,
                                                 bf16* __restrict__ h2) {
    int t = blockIdx.x, tid = threadIdx.x;
    float xs[4], ss = 0.f;
#pragma unroll
    for (int i = 0; i < 4; ++i) {
        int c = tid + i * 256;
        float sh = b2f(mod[(size_t)t * 2048 + c]);
        float sc = b2f(mod[(size_t)t * 2048 + 1024 + c]);
        float v = x1[(size_t)t * D_ + c] * (1.f + sc) + sh;
        xs[i] = v; ss += v * v;
        x1[(size_t)t * D_ + c] = v;
    }
    __shared__ float red[4];
#pragma unroll
    for (int off = 32; off > 0; off >>= 1) ss += __shfl_xor(ss, off, 64);
    if ((tid & 63) == 0) red[tid >> 6] = ss;
    __syncthreads();
    ss = red[0] + red[1] + red[2] + red[3];
    float inv = rsqrtf(ss * (1.f / D_) + 1e-6f);
#pragma unroll
    for (int i = 0; i < 4; ++i) {
        int c = tid + i * 256;
        h2[(size_t)t * D_ + c] = f2b(xs[i] * inv * w[c]);
    }
}

// ------------- ae1: [NTOK,16] @ [16,1024] + b, SiLU (fp32 in, bf16 out) -----
__global__ __launch_bounds__(256) void ae1_k(const float* __restrict__ actions,
                                             const float* __restrict__ w,
                                             const float* __restrict__ b,
                                             bf16* __restrict__ out) {
    int t = blockIdx.x, tid = threadIdx.x;
    float av[16];
#pragma unroll
    for (int a = 0; a < 16; ++a) av[a] = actions[(size_t)t * 16 + a];
#pragma unroll
    for (int i = 0; i < 4; ++i) {
        int n = tid + i * 256;
        float acc = b[n];
#pragma unroll
        for (int a = 0; a < 16; ++a) acc += av[a] * w[a * D_ + n];
        out[(size_t)t * D_ + n] = f2b(acc / (1.f + expf(-acc)));
    }
}

// ---- weight prep: fp32 W[K][N] (row stride ldw) -> bf16 WT[N][K], fused -----
struct WD { const float* src; bf16* dst; int K, N, ldw, tiles; };
struct WPack { WD d[8]; };
__global__ __launch_bounds__(256) void wprep_k(WPack p) {
    int bid = blockIdx.x;
    int mi = 0, cum = 0;
#pragma unroll
    for (mi = 0; mi < 8; ++mi) {
        if (bid < cum + p.d[mi].tiles) break;
        cum += p.d[mi].tiles;
    }
    if (mi >= 8) return;
    WD w = p.d[mi];
    int local = bid - cum;
    int tilesK = w.K >> 6;
    int tk = local % tilesK, tn = local / tilesK;
    int k0 = tk * 64, n0 = tn * 64;
    __shared__ short Tt[64 * 72];   // [n][k]
    int t = threadIdx.x;
    int row = t >> 2, seg = t & 3;
    const float* sp = w.src + (size_t)(k0 + row) * w.ldw + n0 + seg * 16;
#pragma unroll
    for (int q = 0; q < 4; ++q) {
        float4_ f = *(const float4_*)(sp + q * 4);
#pragma unroll
        for (int j = 0; j < 4; ++j) Tt[(seg * 16 + q * 4 + j) * 72 + row] = f2s(f[j]);
    }
    __syncthreads();
    bf16* dp = w.dst + (size_t)(n0 + row) * w.K + k0 + seg * 16;
    *(short8*)dp       = *(const short8*)&Tt[row * 72 + seg * 16];
    *(short8*)(dp + 8) = *(const short8*)&Tt[row * 72 + seg * 16 + 8];
}

// ---- concat q_b|k_b|v_b -> biasQKV[3072] ------------------------------------
__global__ __launch_bounds__(256) void bcat_k(const float* __restrict__ qb,
                                              const float* __restrict__ kb,
                                              const float* __restrict__ vb,
                                              float* __restrict__ dst) {
    int i = blockIdx.x * 256 + threadIdx.x;   // grid 12*256 = 3072
    const float* s = (i < 1024) ? qb : (i < 2048) ? kb : vb;
    dst[i] = s[i & 1023];
}

// --------- MFMA GEMM 128x128: C = A[M,K](bf16) @ WT[N,K](bf16) ---------------
// ACT: 0 none, 1 SiLU, 2 GELU(exact). res added after ACT. ldo = out/res stride.
// QKN: fused per-head RMSNorm (HD=64) on cols<2048 of packed QKV output; each
// wave's 64-col span is one head, so a 16-lane shuffle gives the head sum-sq.
template <int ACT, int QKN, typename ResT, typename OutT>
__global__ __launch_bounds__(256) void gemm_k(const bf16* __restrict__ A,
                                              const bf16* __restrict__ Bt,
                                              const float* __restrict__ bias,
                                              const ResT* __restrict__ res,
                                              OutT* __restrict__ out,
                                              int M, int N, int K, int ldo,
                                              const float* __restrict__ qn_w,
                                              const float* __restrict__ kn_w) {
    __shared__ __align__(16) short As[128 * 64];
    __shared__ __align__(16) short Bs[128 * 64];
    const int tid = threadIdx.x;
    const int bm = blockIdx.y * 128, bn = blockIdx.x * 128;
    const int wave = tid >> 6, lane = tid & 63;
    const int wm = (wave & 1) * 64, wn = (wave >> 1) * 64;
    const int l15 = lane & 15, quad = lane >> 4;
    const int lrow = lane >> 3, lseg = (lane & 7) * 8;
    float4_ acc[4][4] = {};

    for (int k0 = 0; k0 < K; k0 += 64) {
#pragma unroll
        for (int it = 0; it < 4; ++it) {
            int r = it * 32 + wave * 8;
            gl_lds16((const short*)A + (size_t)(bm + r + lrow) * K + k0 + lseg, &As[r * 64]);
            gl_lds16((const short*)Bt + (size_t)(bn + r + lrow) * K + k0 + lseg, &Bs[r * 64]);
        }
        __syncthreads();
#pragma unroll
        for (int kk = 0; kk < 64; kk += 32) {
            short8 af[4], bfr[4];
#pragma unroll
            for (int i = 0; i < 4; ++i)
                af[i] = *(const short8*)&As[(wm + i * 16 + l15) * 64 + kk + quad * 8];
#pragma unroll
            for (int j = 0; j < 4; ++j)
                bfr[j] = *(const short8*)&Bs[(wn + j * 16 + l15) * 64 + kk + quad * 8];
#pragma unroll
            for (int i = 0; i < 4; ++i)
#pragma unroll
                for (int j = 0; j < 4; ++j)
                    acc[i][j] = __builtin_amdgcn_mfma_f32_16x16x32_bf16(af[i], bfr[j], acc[i][j], 0, 0, 0);
        }
        __syncthreads();
    }

    int seg = (bn + wn) >> 10;               // QKN: 0=q, 1=k, >=2 v (no norm)
    float nwv[4];
    if (QKN && seg < 2) {
        const float* nw = seg ? kn_w : qn_w;
#pragma unroll
        for (int j = 0; j < 4; ++j) nwv[j] = nw[j * 16 + l15];
    }

#pragma unroll
    for (int i = 0; i < 4; ++i) {
        float vv[4][4];
#pragma unroll
        for (int j = 0; j < 4; ++j) {
            float bv = bias[bn + wn + j * 16 + l15];
#pragma unroll
            for (int r = 0; r < 4; ++r) vv[j][r] = acc[i][j][r] + bv;
        }
        if (QKN && seg < 2) {
#pragma unroll
            for (int r = 0; r < 4; ++r) {
                float ss = vv[0][r] * vv[0][r] + vv[1][r] * vv[1][r]
                         + vv[2][r] * vv[2][r] + vv[3][r] * vv[3][r];
#pragma unroll
                for (int off = 8; off > 0; off >>= 1) ss += __shfl_xor(ss, off, 16);
                float inv = rsqrtf(ss * (1.f / 64.f) + 1e-6f);
#pragma unroll
                for (int j = 0; j < 4; ++j) vv[j][r] *= inv * nwv[j];
            }
        }
#pragma unroll
        for (int j = 0; j < 4; ++j) {
            int col = bn + wn + j * 16 + l15;
#pragma unroll
            for (int r = 0; r < 4; ++r) {
                int row = bm + wm + i * 16 + quad * 4 + r;
                float v = vv[j][r];
                if (ACT == 1) v = v / (1.f + expf(-v));
                else if (ACT == 2) v = 0.5f * v * (1.f + erff(v * 0.70710678118654752f));
                if (res) v += to_f(res[(size_t)row * ldo + col]);
                store_o(&out[(size_t)row * ldo + col], v);
            }
        }
    }
}

// --------- MFMA GEMM 64x128 tile: for N=1024 GEMMs (512 blocks = 2/CU) -------
template <int ACT, typename ResT, typename OutT>
__global__ __launch_bounds__(256) void gemm64_k(const bf16* __restrict__ A,
                                                const bf16* __restrict__ Bt,
                                                const float* __restrict__ bias,
                                                const ResT* __restrict__ res,
                                                OutT* __restrict__ out,
                                                int M, int N, int K) {
    __shared__ __align__(16) short As[64 * 64];
    __shared__ __align__(16) short Bs[128 * 64];
    const int tid = threadIdx.x;
    const int bm = blockIdx.y * 64, bn = blockIdx.x * 128;
    const int wave = tid >> 6, lane = tid & 63;
    const int wm = (wave & 1) * 32, wn = (wave >> 1) * 64;
    const int l15 = lane & 15, quad = lane >> 4;
    const int lrow = lane >> 3, lseg = (lane & 7) * 8;
    float4_ acc[2][4] = {};

    for (int k0 = 0; k0 < K; k0 += 64) {
#pragma unroll
        for (int it = 0; it < 2; ++it) {
            int r = wave * 16 + it * 8;
            gl_lds16((const short*)A + (size_t)(bm + r + lrow) * K + k0 + lseg, &As[r * 64]);
        }
#pragma unroll
        for (int it = 0; it < 4; ++it) {
            int r = it * 32 + wave * 8;
            gl_lds16((const short*)Bt + (size_t)(bn + r + lrow) * K + k0 + lseg, &Bs[r * 64]);
        }
        __syncthreads();
#pragma unroll
        for (int kk = 0; kk < 64; kk += 32) {
            short8 af[2], bfr[4];
#pragma unroll
            for (int i = 0; i < 2; ++i)
                af[i] = *(const short8*)&As[(wm + i * 16 + l15) * 64 + kk + quad * 8];
#pragma unroll
            for (int j = 0; j < 4; ++j)
                bfr[j] = *(const short8*)&Bs[(wn + j * 16 + l15) * 64 + kk + quad * 8];
#pragma unroll
            for (int i = 0; i < 2; ++i)
#pragma unroll
                for (int j = 0; j < 4; ++j)
                    acc[i][j] = __builtin_amdgcn_mfma_f32_16x16x32_bf16(af[i], bfr[j], acc[i][j], 0, 0, 0);
        }
        __syncthreads();
    }

#pragma unroll
    for (int i = 0; i < 2; ++i)
#pragma unroll
        for (int j = 0; j < 4; ++j) {
            int col = bn + wn + j * 16 + l15;
            float bv = bias[col];
#pragma unroll
            for (int r = 0; r < 4; ++r) {
                int row = bm + wm + i * 16 + quad * 4 + r;
                float v = acc[i][j][r] + bv;
                if (ACT == 1) v = v / (1.f + expf(-v));
                else if (ACT == 2) v = 0.5f * v * (1.f + erff(v * 0.70710678118654752f));
                if (res) v += to_f(res[(size_t)row * N + col]);
                store_o(&out[(size_t)row * N + col], v);
            }
        }
}

// -------------- flash attention, causal, HD=64, q-tile 64, KV tile 64 --------
// NO-MAX softmax: qk-RMSNorm bounds |s| <= ~8.1, so exp(s) cannot overflow
// fp32; l accumulates per-lane, reduced ONCE at the end. No shuffles, no
// rescaling in the inner loop. LPT: bx=0 gets the longest q-block.
// QKV packed [NTOK][3072]; O [NTOK][1024].
__global__ __launch_bounds__(256) void attn_k(const bf16* __restrict__ QKV,
                                              bf16* __restrict__ O) {
    __shared__ __align__(16) short Vt[2][64 * 72];  // [hd][kv]
    __shared__ __align__(16) short Ps[4][16 * 72];  // per-wave [q][kv]
    const int bh = blockIdx.y, b = bh >> 4, h = bh & 15;
    const int q0 = T_ - 64 * (blockIdx.x + 1);      // longest-first
    const int tid = threadIdx.x, wave = tid >> 6, lane = tid & 63;
    const int l15 = lane & 15, quad = lane >> 4;
    const size_t base = (size_t)b * T_ * 3072 + h * 64;
    const short* Qp = (const short*)QKV + base;
    const short* Kp = Qp + 1024;
    const short* Vp = Qp + 2048;

    const int qrow = q0 + wave * 16 + l15;
    short8 qf0 = *(const short8*)(Qp + (size_t)qrow * 3072 + quad * 8);
    short8 qf1 = *(const short8*)(Qp + (size_t)qrow * 3072 + 32 + quad * 8);

    float4_ oacc[4] = {};
    float l_r[4] = {0.f, 0.f, 0.f, 0.f};

    const int vrow = tid >> 2, vseg = tid & 3;
    const int nit = q0 / 64 + 1;

    {   // stage V tile 0 (transposed) into buf 0
        const short* vp = Vp + (size_t)vrow * 3072 + vseg * 16;
        short8 v0 = *(const short8*)vp;
        short8 v1 = *(const short8*)(vp + 8);
#pragma unroll
        for (int j = 0; j < 8; ++j) Vt[0][(vseg * 16 + j) * 72 + vrow] = v0[j];
#pragma unroll
        for (int j = 0; j < 8; ++j) Vt[0][(vseg * 16 + 8 + j) * 72 + vrow] = v1[j];
    }
    __syncthreads();

    for (int it = 0; it < nit; ++it) {
        const int kv0 = it * 64, buf = it & 1;
        if (it + 1 < nit) {   // prefetch next V tile into other buffer
            const short* vp = Vp + (size_t)(kv0 + 64 + vrow) * 3072 + vseg * 16;
            short8 v0 = *(const short8*)vp;
            short8 v1 = *(const short8*)(vp + 8);
#pragma unroll
            for (int j = 0; j < 8; ++j) Vt[buf ^ 1][(vseg * 16 + j) * 72 + vrow] = v0[j];
#pragma unroll
            for (int j = 0; j < 8; ++j) Vt[buf ^ 1][(vseg * 16 + 8 + j) * 72 + vrow] = v1[j];
        }

        // QK^T: K fragments direct from global (coalesced 16B/lane)
        float4_ s[4];
#pragma unroll
        for (int c = 0; c < 4; ++c) {
            const short* kp = Kp + (size_t)(kv0 + c * 16 + l15) * 3072 + quad * 8;
            short8 kb0 = *(const short8*)kp;
            short8 kb1 = *(const short8*)(kp + 32);
            float4_ sc = {};
            sc = __builtin_amdgcn_mfma_f32_16x16x32_bf16(qf0, kb0, sc, 0, 0, 0);
            sc = __builtin_amdgcn_mfma_f32_16x16x32_bf16(qf1, kb1, sc, 0, 0, 0);
            s[c] = sc;
        }

        // mask + exp + per-lane l accumulate (no shuffles, no rescale)
#pragma unroll
        for (int r = 0; r < 4; ++r) {
            int qr = q0 + wave * 16 + quad * 4 + r;
#pragma unroll
            for (int c = 0; c < 4; ++c) {
                int kvi = kv0 + c * 16 + l15;
                float val = (kvi > qr) ? NEG_SENT : s[c][r] * 0.125f;
                float p = __expf(val);           // exp(NEG_SENT) == 0
                s[c][r] = p;
                l_r[r] += p;
            }
        }

        // P: C/D -> A layout via per-wave LDS (wave-synchronous, no barrier)
#pragma unroll
        for (int c = 0; c < 4; ++c)
#pragma unroll
            for (int r = 0; r < 4; ++r)
                Ps[wave][(quad * 4 + r) * 72 + c * 16 + l15] = f2s(s[c][r]);

#pragma unroll
        for (int kk = 0; kk < 64; kk += 32) {
            short8 pf = *(const short8*)&Ps[wave][l15 * 72 + kk + quad * 8];
#pragma unroll
            for (int d = 0; d < 4; ++d) {
                short8 vf = *(const short8*)&Vt[buf][(d * 16 + l15) * 72 + kk + quad * 8];
                oacc[d] = __builtin_amdgcn_mfma_f32_16x16x32_bf16(pf, vf, oacc[d], 0, 0, 0);
            }
        }
        __syncthreads();   // single barrier per KV tile
    }

    // deferred l reduction: sum over the 16-lane group (one row each)
    float linv[4];
#pragma unroll
    for (int r = 0; r < 4; ++r) {
        float l = l_r[r];
#pragma unroll
        for (int off = 8; off > 0; off >>= 1) l += __shfl_xor(l, off, 16);
        linv[r] = 1.f / l;                       // diagonal guarantees l >= exp(s_qq) > 0
    }
#pragma unroll
    for (int d = 0; d < 4; ++d)
#pragma unroll
        for (int r = 0; r < 4; ++r) {
            int qr = q0 + wave * 16 + quad * 4 + r;
            O[(size_t)(b * T_ + qr) * D_ + h * 64 + d * 16 + l15] = f2b(oacc[d][r] * linv[r]);
        }
}

// ---------------------------------------------------------------------------
// Workspace (~70.1 MB):
//   Ah[0,8) ; QKVp[8,32) ([NTOK][3072] bf16) ; AO[32,40)
//   after attn+o-proj: AE1[8,16) AES[16,24) MOD[24,40) ; M1G[8,40) after modnorm
//   weights [40,70): WTqkv 40 WTo 46 WTae2 48 WTmod 50 WTm1 54 WTm2 62
//   biasQKV at 70MB. X1 (fp32 residual) lives in d_out.
extern "C" void kernel_launch(void* const* d_in, const int* in_sizes, int n_in,
                              void* d_out, int out_size, void* d_ws, size_t ws_size,
                              hipStream_t stream) {
    const float* x     = (const float*)d_in[0];
    const float* acts  = (const float*)d_in[1];
    const float* n1_w  = (const float*)d_in[2];
    const float* n2_w  = (const float*)d_in[3];
    const float* q_w   = (const float*)d_in[4];
    const float* q_b   = (const float*)d_in[5];
    const float* k_w   = (const float*)d_in[6];
    const float* k_b   = (const float*)d_in[7];
    const float* v_w   = (const float*)d_in[8];
    const float* v_b   = (const float*)d_in[9];
    const float* qn_w  = (const float*)d_in[10];
    const float* kn_w  = (const float*)d_in[11];
    const float* o_w   = (const float*)d_in[12];
    const float* o_b   = (const float*)d_in[13];
    const float* ae1_w = (const float*)d_in[14];
    const float* ae1_b = (const float*)d_in[15];
    const float* ae2_w = (const float*)d_in[16];
    const float* ae2_b = (const float*)d_in[17];
    const float* mod_w = (const float*)d_in[18];
    const float* mod_b = (const float*)d_in[19];
    const float* m1_w  = (const float*)d_in[20];
    const float* m1_b  = (const float*)d_in[21];
    const float* m2_w  = (const float*)d_in[22];
    const float* m2_b  = (const float*)d_in[23];
    float* out = (float*)d_out;

    char* ws = (char*)d_ws;
    const size_t MB = 1ull << 20;
    bf16*  Ah   = (bf16*)(ws + 0);
    bf16*  QKVp = (bf16*)(ws + 8 * MB);    // [NTOK][3072]
    bf16*  AO   = (bf16*)(ws + 32 * MB);
    bf16*  AE1  = (bf16*)(ws + 8 * MB);
    bf16*  AES  = (bf16*)(ws + 16 * MB);
    bf16*  MOD  = (bf16*)(ws + 24 * MB);
    bf16*  M1G  = (bf16*)(ws + 8 * MB);
    float* X1   = out;

    bf16* WTqkv = (bf16*)(ws + 40 * MB);   // q|k|v contiguous -> [3072][1024]
    bf16* WTo   = (bf16*)(ws + 46 * MB);
    bf16* WTae2 = (bf16*)(ws + 48 * MB);
    bf16* WTmod = (bf16*)(ws + 50 * MB);   // [2048][1024]
    bf16* WTm1  = (bf16*)(ws + 54 * MB);   // [4096][1024]
    bf16* WTm2  = (bf16*)(ws + 62 * MB);   // [1024][4096]
    float* biasQKV = (float*)(ws + 70 * MB);

    dim3 blk(256);

    WPack p;
    p.d[0] = { q_w,   WTqkv,                1024, 1024, 1024, 256 };
    p.d[1] = { k_w,   WTqkv + 1024 * 1024,  1024, 1024, 1024, 256 };
    p.d[2] = { v_w,   WTqkv + 2048 * 1024,  1024, 1024, 1024, 256 };
    p.d[3] = { o_w,   WTo,   1024, 1024, 1024, 256 };
    p.d[4] = { ae2_w, WTae2, 1024, 1024, 1024, 256 };
    p.d[5] = { mod_w, WTmod, 1024, 2048, 4096, 512 };
    p.d[6] = { m1_w,  WTm1,  1024, 4096, 4096, 1024 };
    p.d[7] = { m2_w,  WTm2,  4096, 1024, 1024, 1024 };
    wprep_k<<<3840, blk, 0, stream>>>(p);
    bcat_k<<<12, blk, 0, stream>>>(q_b, k_b, v_b, biasQKV);

    rmsnorm_k<<<NTOK, blk, 0, stream>>>(x, n1_w, Ah);
    gemm_k<0, 1, float, bf16><<<dim3(24, 32), blk, 0, stream>>>(Ah, WTqkv, biasQKV, (const float*)nullptr, QKVp, NTOK, 3072, 1024, 3072, qn_w, kn_w);
    attn_k<<<dim3(T_ / 64, B_ * H_), blk, 0, stream>>>(QKVp, AO);
    gemm64_k<0, float, float><<<dim3(8, 64), blk, 0, stream>>>(AO, WTo, o_b, x, X1, NTOK, 1024, 1024);
    ae1_k<<<NTOK, blk, 0, stream>>>(acts, ae1_w, ae1_b, AE1);
    gemm64_k<1, float, bf16><<<dim3(8, 64), blk, 0, stream>>>(AE1, WTae2, ae2_b, (const float*)nullptr, AES, NTOK, 1024, 1024);
    gemm_k<0, 0, float, bf16><<<dim3(16, 32), blk, 0, stream>>>(AES, WTmod, mod_b, (const float*)nullptr, MOD, NTOK, 2048, 1024, 2048, nullptr, nullptr);
    modnorm_k<<<NTOK, blk, 0, stream>>>(X1, MOD, n2_w, Ah);
    gemm_k<2, 0, float, bf16><<<dim3(32, 32), blk, 0, stream>>>(Ah, WTm1, m1_b, (const float*)nullptr, M1G, NTOK, 4096, 1024, 4096, nullptr, nullptr);
    gemm64_k<0, float, float><<<dim3(8, 64), blk, 0, stream>>>(M1G, WTm2, m2_b, X1, out, NTOK, 1024, 4096);
}